// Round 6
// baseline (222.228 us; speedup 1.0000x reference)
//
#include <hip/hip_runtime.h>
#include <math.h>

#define BBATCH 64
#define LL 200
#define DD 300
#define PP 16
#define EPSV 1e-12f
#define KG 320          // K padded to 10 chunks of 32
#define PS 328          // LDS row stride (halfs): 656 B = 4-bank row shift, 2-way alias free
#define NCH 10

typedef _Float16 f16x8 __attribute__((ext_vector_type(8)));
typedef float f32x4v __attribute__((ext_vector_type(4)));

#define MFMA16(A, B, C) __builtin_amdgcn_mfma_f32_16x16x32_f16((A), (B), (C), 0, 0, 0)

// ---------------- prep: pure streaming f32->f16 (K-pad 300->320) + ksqt frag table ------
__global__ __launch_bounds__(256) void prep_kernel(const float* __restrict__ s1,
                                                   const float* __restrict__ s2,
                                                   const float* __restrict__ kern,
                                                   _Float16* __restrict__ h1,
                                                   _Float16* __restrict__ h2,
                                                   _Float16* __restrict__ ksqt) {
    const int NG = BBATCH * LL * (KG / 8);   // 512000 f16x8 groups per tensor
    int gid = blockIdx.x * 256 + threadIdx.x;

    // ksqt[((ch*4+quad)*16+p)*8+e] = f16(kp[p][ch*32+quad*8+e]^2)
    if (gid < 640) {
        int p = gid & 15, quad = (gid >> 4) & 3, ch = gid >> 6;
        int k0 = ch * 32 + quad * 8;
        f16x8 h;
#pragma unroll
        for (int e = 0; e < 8; e++) {
            int k = k0 + e;
            float kv = (k < DD) ? kern[p * DD + k] : 0.f;
            h[e] = (_Float16)(kv * kv);
        }
        *(f16x8*)&ksqt[gid * 8] = h;
    }

    for (int idx = gid; idx < 2 * NG; idx += gridDim.x * 256) {
        int which = idx >= NG;
        int g = which ? idx - NG : idx;
        int row = g / 40;                 // combined b*200+row, 0..12799
        int q = g - row * 40;
        const float* src = (which ? s2 : s1) + (size_t)row * DD;
        _Float16* dst = (which ? h2 : h1) + (size_t)row * KG + q * 8;
        int k0 = q * 8;
        f16x8 h;
        if (k0 + 8 <= DD) {
            float4 a = *(const float4*)&src[k0];
            float4 c = *(const float4*)&src[k0 + 4];
            h[0] = (_Float16)a.x; h[1] = (_Float16)a.y; h[2] = (_Float16)a.z; h[3] = (_Float16)a.w;
            h[4] = (_Float16)c.x; h[5] = (_Float16)c.y; h[6] = (_Float16)c.z; h[7] = (_Float16)c.w;
        } else {
#pragma unroll
            for (int e = 0; e < 8; e++) {
                int k = k0 + e;
                h[e] = (k < DD) ? (_Float16)src[k] : (_Float16)0.f;
            }
        }
        *(f16x8*)dst = h;
    }
}

// ---------------- maxsim: full-K LDS tiles, in-block MFMA norms, 8 waves ----------------
// block (b, iblk, jblk): A 128i x 320k, B 112j x 320k f16 LDS-resident (161 KB, 1 blk/CU).
// waves: ws = w&3 -> i rows [ws*32, ws*32+32); wp = w>>2 -> p half [wp*8, wp*8+8).
// norms: n^2[r,p] = MFMA(sq(frags), ksq-frags); n1inv in regs (lane-exact), n2inv via LDS.
__global__ __launch_bounds__(512, 2) void maxsim_kernel(const _Float16* __restrict__ h1,
                                                        const _Float16* __restrict__ h2,
                                                        const _Float16* __restrict__ ksqt,
                                                        float* __restrict__ part) {
    extern __shared__ __align__(16) char smem[];
    _Float16* h1s = (_Float16*)smem;          // 128*PS halfs
    _Float16* h2s = h1s + 128 * PS;           // 112*PS halfs
    _Float16* n2s = h2s + 112 * PS;           // [112][16] f16

    const int blk  = blockIdx.x;
    const int b    = blk >> 2;
    const int iblk = (blk >> 1) & 1;
    const int jblk = blk & 1;
    const int i0   = iblk ? 72 : 0;           // overlapped windows: no row masks anywhere
    const int j0   = jblk ? 88 : 0;
    const int t    = threadIdx.x;

    // ---- stage tiles ----
    {
        const _Float16* g1 = h1 + ((size_t)b * LL + i0) * KG;
        for (int idx = t; idx < 128 * 40; idx += 512) {
            int r = idx / 40, q = idx - r * 40;
            *(f16x8*)&h1s[r * PS + q * 8] = *(const f16x8*)&g1[(size_t)idx * 8];
        }
        const _Float16* g2 = h2 + ((size_t)b * LL + j0) * KG;
        for (int idx = t; idx < 112 * 40; idx += 512) {
            int r = idx / 40, q = idx - r * 40;
            *(f16x8*)&h2s[r * PS + q * 8] = *(const f16x8*)&g2[(size_t)idx * 8];
        }
    }
    __syncthreads();

    const int lane = t & 63;
    const int w    = t >> 6;
    const int ws   = w & 3;
    const int wp   = w >> 2;
    const int c    = lane & 15;
    const int quad = lane >> 4;

    // ---- norms via MFMA of squares ----
    float n1inv_reg[2][4];
    {
        f32x4v nacc0 = (f32x4v)0.f, nacc1 = (f32x4v)0.f;
#pragma unroll
        for (int ch = 0; ch < NCH; ch++) {
            f16x8 kb = *(const f16x8*)&ksqt[((ch * 4 + quad) * 16 + c) * 8];
            f16x8 a0 = *(const f16x8*)&h1s[(ws * 32 + c) * PS + ch * 32 + quad * 8];
            f16x8 a1 = *(const f16x8*)&h1s[(ws * 32 + 16 + c) * PS + ch * 32 + quad * 8];
            nacc0 = MFMA16(a0 * a0, kb, nacc0);
            nacc1 = MFMA16(a1 * a1, kb, nacc1);
        }
        // lane (c=p, quad) holds rows ws*32 + it*16 + quad*4 + r — exactly its epilogue rows
#pragma unroll
        for (int r = 0; r < 4; r++) {
            n1inv_reg[0][r] = rsqrtf(fmaxf(nacc0[r], EPSV));
            n1inv_reg[1][r] = rsqrtf(fmaxf(nacc1[r], EPSV));
        }
    }
    if (w < 7) {   // j-norms: wave w owns jt=w (rows w*16..w*16+15)
        f32x4v nacc = (f32x4v)0.f;
#pragma unroll
        for (int ch = 0; ch < NCH; ch++) {
            f16x8 kb = *(const f16x8*)&ksqt[((ch * 4 + quad) * 16 + c) * 8];
            f16x8 bq = *(const f16x8*)&h2s[(w * 16 + c) * PS + ch * 32 + quad * 8];
            nacc = MFMA16(bq * bq, kb, nacc);
        }
#pragma unroll
        for (int r = 0; r < 4; r++)
            n2s[(w * 16 + quad * 4 + r) * 16 + c] = (_Float16)rsqrtf(fmaxf(nacc[r], EPSV));
    }
    __syncthreads();

    // ---- main: for each p-pair in this wave's half ----
    const int pbase = wp * 8;
    for (int pp = 0; pp < 4; pp++) {
        const int p0 = pbase + pp * 2;
        f32x4v acc[2][2][7];   // [pq][it][jt]
#pragma unroll
        for (int pq = 0; pq < 2; pq++)
#pragma unroll
            for (int it = 0; it < 2; it++)
#pragma unroll
                for (int jt = 0; jt < 7; jt++) acc[pq][it][jt] = (f32x4v)0.f;

        f16x8 kqn0 = *(const f16x8*)&ksqt[((0 * 4 + quad) * 16 + p0) * 8];
        f16x8 kqn1 = *(const f16x8*)&ksqt[((0 * 4 + quad) * 16 + p0 + 1) * 8];

#pragma unroll
        for (int ch = 0; ch < NCH; ch++) {
            f16x8 kq0 = kqn0, kq1 = kqn1;
            if (ch < NCH - 1) {   // prefetch next chunk's ksq frags (L1-hot 10 KB table)
                kqn0 = *(const f16x8*)&ksqt[(((ch + 1) * 4 + quad) * 16 + p0) * 8];
                kqn1 = *(const f16x8*)&ksqt[(((ch + 1) * 4 + quad) * 16 + p0 + 1) * 8];
            }
            f16x8 a0 = *(const f16x8*)&h1s[(ws * 32 + c) * PS + ch * 32 + quad * 8];
            f16x8 a1 = *(const f16x8*)&h1s[(ws * 32 + 16 + c) * PS + ch * 32 + quad * 8];
            f16x8 sa00 = a0 * kq0, sa10 = a1 * kq0;   // fold ksq into A: 4 muls vs 14 on B
            f16x8 sa01 = a0 * kq1, sa11 = a1 * kq1;
#pragma unroll
            for (int jt = 0; jt < 7; jt++) {
                f16x8 hb = *(const f16x8*)&h2s[(jt * 16 + c) * PS + ch * 32 + quad * 8];
                acc[0][0][jt] = MFMA16(sa00, hb, acc[0][0][jt]);
                acc[0][1][jt] = MFMA16(sa10, hb, acc[0][1][jt]);
                acc[1][0][jt] = MFMA16(sa01, hb, acc[1][0][jt]);
                acc[1][1][jt] = MFMA16(sa11, hb, acc[1][1][jt]);
            }
        }

        // epilogue: scale cols by n2inv[j,p], max over j, apply n1inv, store
#pragma unroll
        for (int pq = 0; pq < 2; pq++) {
            const int p = p0 + pq;
            float rmax[2][4];
#pragma unroll
            for (int it = 0; it < 2; it++)
#pragma unroll
                for (int r = 0; r < 4; r++) rmax[it][r] = -INFINITY;
#pragma unroll
            for (int jt = 0; jt < 7; jt++) {
                float n2 = (float)n2s[(jt * 16 + c) * 16 + p];
#pragma unroll
                for (int it = 0; it < 2; it++)
#pragma unroll
                    for (int r = 0; r < 4; r++)
                        rmax[it][r] = fmaxf(rmax[it][r], acc[pq][it][jt][r] * n2);
            }
#pragma unroll
            for (int m = 1; m <= 8; m <<= 1)
#pragma unroll
                for (int it = 0; it < 2; it++)
#pragma unroll
                    for (int r = 0; r < 4; r++)
                        rmax[it][r] = fmaxf(rmax[it][r], __shfl_xor(rmax[it][r], m));

            if (c == p) {   // this lane holds n1inv for exactly these rows
#pragma unroll
                for (int it = 0; it < 2; it++)
#pragma unroll
                    for (int r = 0; r < 4; r++) {
                        int i = i0 + ws * 32 + it * 16 + quad * 4 + r;   // always < 200
                        part[((size_t)jblk * BBATCH + b) * (LL * PP) + (size_t)i * PP + p] =
                            rmax[it][r] * n1inv_reg[it][r];
                    }
            }
        }
    }
}

// ---------------- reduce: out = max over the two j-windows ------------------------------
__global__ __launch_bounds__(256) void reduce_kernel(const float* __restrict__ part,
                                                     float* __restrict__ out) {
    int tid = blockIdx.x * 256 + threadIdx.x;
    if (tid >= BBATCH * LL * PP) return;
    out[tid] = fmaxf(part[tid], part[(size_t)BBATCH * LL * PP + tid]);
}

extern "C" void kernel_launch(void* const* d_in, const int* in_sizes, int n_in,
                              void* d_out, int out_size, void* d_ws, size_t ws_size,
                              hipStream_t stream) {
    const float* sent1  = (const float*)d_in[0];   // (64,200,300) f32
    const float* sent2  = (const float*)d_in[1];   // (64,200,300) f32
    const float* kernel = (const float*)d_in[2];   // (16,300)     f32
    float* out = (float*)d_out;                    // (64,200,16)  f32

    char* ws = (char*)d_ws;
    _Float16* h1   = (_Float16*)ws;  ws += (size_t)BBATCH * LL * KG * 2;   // 8.19 MB
    _Float16* h2   = (_Float16*)ws;  ws += (size_t)BBATCH * LL * KG * 2;   // 8.19 MB
    _Float16* ksqt = (_Float16*)ws;  ws += 640 * 8 * 2;                    // 10 KB
    float*    part = (float*)ws;     // 2*64*200*16 f32 = 1.64 MB  (total ~18 MB)

    prep_kernel<<<2048, 256, 0, stream>>>(sent1, sent2, kernel, h1, h2, ksqt);

    const int lds_bytes = (128 * PS + 112 * PS + 112 * PP) * 2;   // 161,024 B
    hipFuncSetAttribute((const void*)maxsim_kernel,
                        hipFuncAttributeMaxDynamicSharedMemorySize, lds_bytes);
    maxsim_kernel<<<dim3(256, 1, 1), 512, lds_bytes, stream>>>(h1, h2, ksqt, part);

    int nout = BBATCH * LL * PP;
    reduce_kernel<<<(nout + 255) / 256, 256, 0, stream>>>(part, out);
}

// Round 7
// 209.673 us; speedup vs baseline: 1.0599x; 1.0599x over previous
//
#include <hip/hip_runtime.h>
#include <math.h>

#define BBATCH 64
#define LL 200
#define DD 300
#define PP 16
#define EPSV 1e-12f
#define KG 320          // K padded to 10 chunks of 32
#define PS 328          // LDS row stride (halfs): 656 B = 4-bank row shift, 2-way alias free
#define NCH 10

typedef _Float16 f16x8 __attribute__((ext_vector_type(8)));
typedef float f32x4v __attribute__((ext_vector_type(4)));

#define MFMA16(A, B, C) __builtin_amdgcn_mfma_f32_16x16x32_f16((A), (B), (C), 0, 0, 0)

// ---------------- prep: pure streaming f32->f16 (K-pad 300->320) + ksqt frag table ------
__global__ __launch_bounds__(256) void prep_kernel(const float* __restrict__ s1,
                                                   const float* __restrict__ s2,
                                                   const float* __restrict__ kern,
                                                   _Float16* __restrict__ h1,
                                                   _Float16* __restrict__ h2,
                                                   _Float16* __restrict__ ksqt) {
    const int NG = BBATCH * LL * (KG / 8);   // 512000 f16x8 groups per tensor
    int gid = blockIdx.x * 256 + threadIdx.x;

    // ksqt[((ch*4+quad)*16+p)*8+e] = f16(kp[p][ch*32+quad*8+e]^2)
    if (gid < 640) {
        int p = gid & 15, quad = (gid >> 4) & 3, ch = gid >> 6;
        int k0 = ch * 32 + quad * 8;
        f16x8 h;
#pragma unroll
        for (int e = 0; e < 8; e++) {
            int k = k0 + e;
            float kv = (k < DD) ? kern[p * DD + k] : 0.f;
            h[e] = (_Float16)(kv * kv);
        }
        *(f16x8*)&ksqt[gid * 8] = h;
    }

    for (int idx = gid; idx < 2 * NG; idx += gridDim.x * 256) {
        int which = idx >= NG;
        int g = which ? idx - NG : idx;
        int row = g / 40;                 // combined b*200+row, 0..12799
        int q = g - row * 40;
        const float* src = (which ? s2 : s1) + (size_t)row * DD;
        _Float16* dst = (which ? h2 : h1) + (size_t)row * KG + q * 8;
        int k0 = q * 8;
        f16x8 h;
        if (k0 + 8 <= DD) {
            float4 a = *(const float4*)&src[k0];
            float4 c = *(const float4*)&src[k0 + 4];
            h[0] = (_Float16)a.x; h[1] = (_Float16)a.y; h[2] = (_Float16)a.z; h[3] = (_Float16)a.w;
            h[4] = (_Float16)c.x; h[5] = (_Float16)c.y; h[6] = (_Float16)c.z; h[7] = (_Float16)c.w;
        } else {
#pragma unroll
            for (int e = 0; e < 8; e++) {
                int k = k0 + e;
                h[e] = (k < DD) ? (_Float16)src[k] : (_Float16)0.f;
            }
        }
        *(f16x8*)dst = h;
    }
}

// ---------------- maxsim: full-K LDS tiles, in-block MFMA norms, 8 waves ----------------
// block (b, iblk, jblk): A 128i x 320k, B 112j x 320k f16 LDS-resident (161 KB, 1 blk/CU).
// waves: ws = w&3 -> i rows [ws*32, ws*32+32); wp = w>>2 -> p half [wp*8, wp*8+8).
// j-tiles processed in two groups (4 + 3) to keep acc at 64 VGPRs (R6's 112 spilled
// under the 128-VGPR cap that __launch_bounds__(512,2) imposed — use plain (512)).
__global__ __launch_bounds__(512) void maxsim_kernel(const _Float16* __restrict__ h1,
                                                     const _Float16* __restrict__ h2,
                                                     const _Float16* __restrict__ ksqt,
                                                     float* __restrict__ part) {
    extern __shared__ __align__(16) char smem[];
    _Float16* h1s = (_Float16*)smem;          // 128*PS halfs
    _Float16* h2s = h1s + 128 * PS;           // 112*PS halfs
    _Float16* n2s = h2s + 112 * PS;           // [112][16] f16

    const int blk  = blockIdx.x;
    const int b    = blk >> 2;
    const int iblk = (blk >> 1) & 1;
    const int jblk = blk & 1;
    const int i0   = iblk ? 72 : 0;           // overlapped windows: no row masks anywhere
    const int j0   = jblk ? 88 : 0;
    const int t    = threadIdx.x;

    // ---- stage tiles ----
    {
        const _Float16* g1 = h1 + ((size_t)b * LL + i0) * KG;
        for (int idx = t; idx < 128 * 40; idx += 512) {
            int r = idx / 40, q = idx - r * 40;
            *(f16x8*)&h1s[r * PS + q * 8] = *(const f16x8*)&g1[(size_t)idx * 8];
        }
        const _Float16* g2 = h2 + ((size_t)b * LL + j0) * KG;
        for (int idx = t; idx < 112 * 40; idx += 512) {
            int r = idx / 40, q = idx - r * 40;
            *(f16x8*)&h2s[r * PS + q * 8] = *(const f16x8*)&g2[(size_t)idx * 8];
        }
    }
    __syncthreads();

    const int lane = t & 63;
    const int w    = t >> 6;
    const int ws   = w & 3;
    const int wp   = w >> 2;
    const int c    = lane & 15;
    const int quad = lane >> 4;

    // ---- norms via MFMA of squares ----
    float n1inv_reg[2][4];
    {
        f32x4v nacc0 = (f32x4v)0.f, nacc1 = (f32x4v)0.f;
#pragma unroll
        for (int ch = 0; ch < NCH; ch++) {
            f16x8 kb = *(const f16x8*)&ksqt[((ch * 4 + quad) * 16 + c) * 8];
            f16x8 a0 = *(const f16x8*)&h1s[(ws * 32 + c) * PS + ch * 32 + quad * 8];
            f16x8 a1 = *(const f16x8*)&h1s[(ws * 32 + 16 + c) * PS + ch * 32 + quad * 8];
            nacc0 = MFMA16(a0 * a0, kb, nacc0);
            nacc1 = MFMA16(a1 * a1, kb, nacc1);
        }
        // lane (c=p, quad) holds rows ws*32 + it*16 + quad*4 + r — exactly its epilogue rows
#pragma unroll
        for (int r = 0; r < 4; r++) {
            n1inv_reg[0][r] = rsqrtf(fmaxf(nacc0[r], EPSV));
            n1inv_reg[1][r] = rsqrtf(fmaxf(nacc1[r], EPSV));
        }
    }
    if (w < 7) {   // j-norms: wave w owns jt=w (rows w*16..w*16+15)
        f32x4v nacc = (f32x4v)0.f;
#pragma unroll
        for (int ch = 0; ch < NCH; ch++) {
            f16x8 kb = *(const f16x8*)&ksqt[((ch * 4 + quad) * 16 + c) * 8];
            f16x8 bq = *(const f16x8*)&h2s[(w * 16 + c) * PS + ch * 32 + quad * 8];
            nacc = MFMA16(bq * bq, kb, nacc);
        }
#pragma unroll
        for (int r = 0; r < 4; r++)
            n2s[(w * 16 + quad * 4 + r) * 16 + c] = (_Float16)rsqrtf(fmaxf(nacc[r], EPSV));
    }
    __syncthreads();

    // ---- main: for each p-pair in this wave's half; j-tiles in two groups (4+3) ----
    const int pbase = wp * 8;
    for (int pp = 0; pp < 4; pp++) {
        const int p0 = pbase + pp * 2;

        float rmax[2][2][4];   // [pq][it][r]
#pragma unroll
        for (int pq = 0; pq < 2; pq++)
#pragma unroll
            for (int it = 0; it < 2; it++)
#pragma unroll
                for (int r = 0; r < 4; r++) rmax[pq][it][r] = -INFINITY;

#pragma unroll
        for (int jg = 0; jg < 2; jg++) {
            const int jt0 = jg * 4;
            const int njt = jg ? 3 : 4;

            f32x4v acc[2][2][4];   // [pq][it][jtl] — 64 VGPRs max
#pragma unroll
            for (int pq = 0; pq < 2; pq++)
#pragma unroll
                for (int it = 0; it < 2; it++)
#pragma unroll
                    for (int jtl = 0; jtl < 4; jtl++) acc[pq][it][jtl] = (f32x4v)0.f;

            f16x8 kqn0 = *(const f16x8*)&ksqt[((0 * 4 + quad) * 16 + p0) * 8];
            f16x8 kqn1 = *(const f16x8*)&ksqt[((0 * 4 + quad) * 16 + p0 + 1) * 8];

#pragma unroll
            for (int ch = 0; ch < NCH; ch++) {
                f16x8 kq0 = kqn0, kq1 = kqn1;
                if (ch < NCH - 1) {   // prefetch next chunk's ksq frags (L1-hot 10 KB table)
                    kqn0 = *(const f16x8*)&ksqt[(((ch + 1) * 4 + quad) * 16 + p0) * 8];
                    kqn1 = *(const f16x8*)&ksqt[(((ch + 1) * 4 + quad) * 16 + p0 + 1) * 8];
                }
                f16x8 a0 = *(const f16x8*)&h1s[(ws * 32 + c) * PS + ch * 32 + quad * 8];
                f16x8 a1 = *(const f16x8*)&h1s[(ws * 32 + 16 + c) * PS + ch * 32 + quad * 8];
                f16x8 sa00 = a0 * kq0, sa10 = a1 * kq0;   // fold ksq into A
                f16x8 sa01 = a0 * kq1, sa11 = a1 * kq1;
#pragma unroll
                for (int jtl = 0; jtl < njt; jtl++) {
                    f16x8 hb = *(const f16x8*)&h2s[((jt0 + jtl) * 16 + c) * PS + ch * 32 + quad * 8];
                    acc[0][0][jtl] = MFMA16(sa00, hb, acc[0][0][jtl]);
                    acc[0][1][jtl] = MFMA16(sa10, hb, acc[0][1][jtl]);
                    acc[1][0][jtl] = MFMA16(sa01, hb, acc[1][0][jtl]);
                    acc[1][1][jtl] = MFMA16(sa11, hb, acc[1][1][jtl]);
                }
            }

            // fold this j-group into rmax (C/D: col=lane&15=j-local, row=quad*4+r=i-local)
#pragma unroll
            for (int pq = 0; pq < 2; pq++) {
                const int p = p0 + pq;
#pragma unroll
                for (int jtl = 0; jtl < njt; jtl++) {
                    float n2 = (float)n2s[((jt0 + jtl) * 16 + c) * 16 + p];
#pragma unroll
                    for (int it = 0; it < 2; it++)
#pragma unroll
                        for (int r = 0; r < 4; r++)
                            rmax[pq][it][r] = fmaxf(rmax[pq][it][r], acc[pq][it][jtl][r] * n2);
                }
            }
        }

        // cross-lane max over the 16 j-columns, then store (lane c==p owns its rows' n1inv)
#pragma unroll
        for (int m = 1; m <= 8; m <<= 1)
#pragma unroll
            for (int pq = 0; pq < 2; pq++)
#pragma unroll
                for (int it = 0; it < 2; it++)
#pragma unroll
                    for (int r = 0; r < 4; r++)
                        rmax[pq][it][r] = fmaxf(rmax[pq][it][r], __shfl_xor(rmax[pq][it][r], m));

#pragma unroll
        for (int pq = 0; pq < 2; pq++) {
            const int p = p0 + pq;
            if (c == p) {
#pragma unroll
                for (int it = 0; it < 2; it++)
#pragma unroll
                    for (int r = 0; r < 4; r++) {
                        int i = i0 + ws * 32 + it * 16 + quad * 4 + r;   // always < 200
                        part[((size_t)jblk * BBATCH + b) * (LL * PP) + (size_t)i * PP + p] =
                            rmax[pq][it][r] * n1inv_reg[it][r];
                    }
            }
        }
    }
}

// ---------------- reduce: out = max over the two j-windows ------------------------------
__global__ __launch_bounds__(256) void reduce_kernel(const float* __restrict__ part,
                                                     float* __restrict__ out) {
    int tid = blockIdx.x * 256 + threadIdx.x;
    if (tid >= BBATCH * LL * PP) return;
    out[tid] = fmaxf(part[tid], part[(size_t)BBATCH * LL * PP + tid]);
}

extern "C" void kernel_launch(void* const* d_in, const int* in_sizes, int n_in,
                              void* d_out, int out_size, void* d_ws, size_t ws_size,
                              hipStream_t stream) {
    const float* sent1  = (const float*)d_in[0];   // (64,200,300) f32
    const float* sent2  = (const float*)d_in[1];   // (64,200,300) f32
    const float* kernel = (const float*)d_in[2];   // (16,300)     f32
    float* out = (float*)d_out;                    // (64,200,16)  f32

    char* ws = (char*)d_ws;
    _Float16* h1   = (_Float16*)ws;  ws += (size_t)BBATCH * LL * KG * 2;   // 8.19 MB
    _Float16* h2   = (_Float16*)ws;  ws += (size_t)BBATCH * LL * KG * 2;   // 8.19 MB
    _Float16* ksqt = (_Float16*)ws;  ws += 640 * 8 * 2;                    // 10 KB
    float*    part = (float*)ws;     // 2*64*200*16 f32 = 1.64 MB  (total ~18 MB)

    prep_kernel<<<2048, 256, 0, stream>>>(sent1, sent2, kernel, h1, h2, ksqt);

    const int lds_bytes = (128 * PS + 112 * PS + 112 * PP) * 2;   // 161,024 B
    hipFuncSetAttribute((const void*)maxsim_kernel,
                        hipFuncAttributeMaxDynamicSharedMemorySize, lds_bytes);
    maxsim_kernel<<<dim3(256, 1, 1), 512, lds_bytes, stream>>>(h1, h2, ksqt, part);

    int nout = BBATCH * LL * PP;
    reduce_kernel<<<(nout + 255) / 256, 256, 0, stream>>>(part, out);
}

// Round 8
// 208.325 us; speedup vs baseline: 1.0667x; 1.0065x over previous
//
#include <hip/hip_runtime.h>
#include <math.h>

#define BBATCH 64
#define LL 200
#define DD 300
#define PP 16
#define EPSV 1e-12f
#define KG 320          // K padded to 10 chunks of 32
#define PS 328          // LDS row stride (halfs): 656 B = 4-bank row shift, 2-way alias free
#define NCH 10

typedef _Float16 f16x8 __attribute__((ext_vector_type(8)));
typedef float f32x4v __attribute__((ext_vector_type(4)));

#define MFMA16(A, B, C) __builtin_amdgcn_mfma_f32_16x16x32_f16((A), (B), (C), 0, 0, 0)

// ---------------- prep: pure streaming f32->f16 (K-pad 300->320) + ksqt frag table ------
__global__ __launch_bounds__(256) void prep_kernel(const float* __restrict__ s1,
                                                   const float* __restrict__ s2,
                                                   const float* __restrict__ kern,
                                                   _Float16* __restrict__ h1,
                                                   _Float16* __restrict__ h2,
                                                   _Float16* __restrict__ ksqt) {
    const int NG = BBATCH * LL * (KG / 8);   // 512000 f16x8 groups per tensor
    int gid = blockIdx.x * 256 + threadIdx.x;

    // ksqt[((ch*4+quad)*16+p)*8+e] = f16(kp[p][ch*32+quad*8+e]^2)
    if (gid < 640) {
        int p = gid & 15, quad = (gid >> 4) & 3, ch = gid >> 6;
        int k0 = ch * 32 + quad * 8;
        f16x8 h;
#pragma unroll
        for (int e = 0; e < 8; e++) {
            int k = k0 + e;
            float kv = (k < DD) ? kern[p * DD + k] : 0.f;
            h[e] = (_Float16)(kv * kv);
        }
        *(f16x8*)&ksqt[gid * 8] = h;
    }

    for (int idx = gid; idx < 2 * NG; idx += gridDim.x * 256) {
        int which = idx >= NG;
        int g = which ? idx - NG : idx;
        int row = g / 40;                 // combined b*200+row, 0..12799
        int q = g - row * 40;
        const float* src = (which ? s2 : s1) + (size_t)row * DD;
        _Float16* dst = (which ? h2 : h1) + (size_t)row * KG + q * 8;
        int k0 = q * 8;
        f16x8 h;
        if (k0 + 8 <= DD) {
            float4 a = *(const float4*)&src[k0];
            float4 c = *(const float4*)&src[k0 + 4];
            h[0] = (_Float16)a.x; h[1] = (_Float16)a.y; h[2] = (_Float16)a.z; h[3] = (_Float16)a.w;
            h[4] = (_Float16)c.x; h[5] = (_Float16)c.y; h[6] = (_Float16)c.z; h[7] = (_Float16)c.w;
        } else {
#pragma unroll
            for (int e = 0; e < 8; e++) {
                int k = k0 + e;
                h[e] = (k < DD) ? (_Float16)src[k] : (_Float16)0.f;
            }
        }
        *(f16x8*)dst = h;
    }
}

// ---------------- maxsim: full-K LDS tiles, in-block MFMA norms, 8 waves ----------------
// block (b, iblk, jblk): A 128i x 320k, B 112j x 320k f16 LDS-resident (161 KB, 1 blk/CU).
// waves: ws = w&3 -> i rows [ws*32, ws*32+32); wp = w>>2 -> p half [wp*8, wp*8+8).
// amdgpu_waves_per_eu(2,2): dynamic LDS hides the 1-block/CU fact from the occupancy
// heuristic, which otherwise targets 4 waves/EU -> 128-VGPR cap -> ~100 VGPRs of spill
// (R6/R7: WRITE_SIZE 170 MB). Pinning 2/EU sets the cap at 256 and stops the spilling.
__global__ __launch_bounds__(512)
__attribute__((amdgpu_waves_per_eu(2, 2)))
void maxsim_kernel(const _Float16* __restrict__ h1,
                   const _Float16* __restrict__ h2,
                   const _Float16* __restrict__ ksqt,
                   float* __restrict__ part) {
    extern __shared__ __align__(16) char smem[];
    _Float16* h1s = (_Float16*)smem;          // 128*PS halfs
    _Float16* h2s = h1s + 128 * PS;           // 112*PS halfs
    _Float16* n2s = h2s + 112 * PS;           // [112][16] f16

    const int blk  = blockIdx.x;
    const int b    = blk >> 2;
    const int iblk = (blk >> 1) & 1;
    const int jblk = blk & 1;
    const int i0   = iblk ? 72 : 0;           // overlapped windows: no row masks anywhere
    const int j0   = jblk ? 88 : 0;
    const int t    = threadIdx.x;

    // ---- stage tiles ----
    {
        const _Float16* g1 = h1 + ((size_t)b * LL + i0) * KG;
        for (int idx = t; idx < 128 * 40; idx += 512) {
            int r = idx / 40, q = idx - r * 40;
            *(f16x8*)&h1s[r * PS + q * 8] = *(const f16x8*)&g1[(size_t)idx * 8];
        }
        const _Float16* g2 = h2 + ((size_t)b * LL + j0) * KG;
        for (int idx = t; idx < 112 * 40; idx += 512) {
            int r = idx / 40, q = idx - r * 40;
            *(f16x8*)&h2s[r * PS + q * 8] = *(const f16x8*)&g2[(size_t)idx * 8];
        }
    }
    __syncthreads();

    const int lane = t & 63;
    const int w    = t >> 6;
    const int ws   = w & 3;
    const int wp   = w >> 2;
    const int c    = lane & 15;
    const int quad = lane >> 4;

    // ---- norms via MFMA of squares ----
    float n1inv_reg[2][4];
    {
        f32x4v nacc0 = (f32x4v)0.f, nacc1 = (f32x4v)0.f;
#pragma unroll
        for (int ch = 0; ch < NCH; ch++) {
            f16x8 kb = *(const f16x8*)&ksqt[((ch * 4 + quad) * 16 + c) * 8];
            f16x8 a0 = *(const f16x8*)&h1s[(ws * 32 + c) * PS + ch * 32 + quad * 8];
            f16x8 a1 = *(const f16x8*)&h1s[(ws * 32 + 16 + c) * PS + ch * 32 + quad * 8];
            nacc0 = MFMA16(a0 * a0, kb, nacc0);
            nacc1 = MFMA16(a1 * a1, kb, nacc1);
        }
        // lane (c=p, quad) holds rows ws*32 + it*16 + quad*4 + r — exactly its epilogue rows
#pragma unroll
        for (int r = 0; r < 4; r++) {
            n1inv_reg[0][r] = rsqrtf(fmaxf(nacc0[r], EPSV));
            n1inv_reg[1][r] = rsqrtf(fmaxf(nacc1[r], EPSV));
        }
    }
    if (w < 7) {   // j-norms: wave w owns jt=w (rows w*16..w*16+15)
        f32x4v nacc = (f32x4v)0.f;
#pragma unroll
        for (int ch = 0; ch < NCH; ch++) {
            f16x8 kb = *(const f16x8*)&ksqt[((ch * 4 + quad) * 16 + c) * 8];
            f16x8 bq = *(const f16x8*)&h2s[(w * 16 + c) * PS + ch * 32 + quad * 8];
            nacc = MFMA16(bq * bq, kb, nacc);
        }
#pragma unroll
        for (int r = 0; r < 4; r++)
            n2s[(w * 16 + quad * 4 + r) * 16 + c] = (_Float16)rsqrtf(fmaxf(nacc[r], EPSV));
    }
    __syncthreads();

    // ---- main: for each p-pair in this wave's half; j-tiles in two groups (4+3) ----
    const int pbase = wp * 8;
    for (int pp = 0; pp < 4; pp++) {
        const int p0 = pbase + pp * 2;

        float rmax[2][2][4];   // [pq][it][r]
#pragma unroll
        for (int pq = 0; pq < 2; pq++)
#pragma unroll
            for (int it = 0; it < 2; it++)
#pragma unroll
                for (int r = 0; r < 4; r++) rmax[pq][it][r] = -INFINITY;

#pragma unroll
        for (int jg = 0; jg < 2; jg++) {
            const int jt0 = jg * 4;
            const int njt = jg ? 3 : 4;

            f32x4v acc[2][2][4];   // [pq][it][jtl] — 64 VGPRs max
#pragma unroll
            for (int pq = 0; pq < 2; pq++)
#pragma unroll
                for (int it = 0; it < 2; it++)
#pragma unroll
                    for (int jtl = 0; jtl < 4; jtl++) acc[pq][it][jtl] = (f32x4v)0.f;

            f16x8 kqn0 = *(const f16x8*)&ksqt[((0 * 4 + quad) * 16 + p0) * 8];
            f16x8 kqn1 = *(const f16x8*)&ksqt[((0 * 4 + quad) * 16 + p0 + 1) * 8];

#pragma unroll
            for (int ch = 0; ch < NCH; ch++) {
                f16x8 kq0 = kqn0, kq1 = kqn1;
                if (ch < NCH - 1) {   // prefetch next chunk's ksq frags (L1-hot 10 KB table)
                    kqn0 = *(const f16x8*)&ksqt[(((ch + 1) * 4 + quad) * 16 + p0) * 8];
                    kqn1 = *(const f16x8*)&ksqt[(((ch + 1) * 4 + quad) * 16 + p0 + 1) * 8];
                }
                f16x8 a0 = *(const f16x8*)&h1s[(ws * 32 + c) * PS + ch * 32 + quad * 8];
                f16x8 a1 = *(const f16x8*)&h1s[(ws * 32 + 16 + c) * PS + ch * 32 + quad * 8];
                f16x8 sa00 = a0 * kq0, sa10 = a1 * kq0;   // fold ksq into A
                f16x8 sa01 = a0 * kq1, sa11 = a1 * kq1;
#pragma unroll
                for (int jtl = 0; jtl < njt; jtl++) {
                    f16x8 hb = *(const f16x8*)&h2s[((jt0 + jtl) * 16 + c) * PS + ch * 32 + quad * 8];
                    acc[0][0][jtl] = MFMA16(sa00, hb, acc[0][0][jtl]);
                    acc[0][1][jtl] = MFMA16(sa10, hb, acc[0][1][jtl]);
                    acc[1][0][jtl] = MFMA16(sa01, hb, acc[1][0][jtl]);
                    acc[1][1][jtl] = MFMA16(sa11, hb, acc[1][1][jtl]);
                }
            }

            // fold this j-group into rmax (C/D: col=lane&15=j-local, row=quad*4+r=i-local)
#pragma unroll
            for (int pq = 0; pq < 2; pq++) {
                const int p = p0 + pq;
#pragma unroll
                for (int jtl = 0; jtl < njt; jtl++) {
                    float n2 = (float)n2s[((jt0 + jtl) * 16 + c) * 16 + p];
#pragma unroll
                    for (int it = 0; it < 2; it++)
#pragma unroll
                        for (int r = 0; r < 4; r++)
                            rmax[pq][it][r] = fmaxf(rmax[pq][it][r], acc[pq][it][jtl][r] * n2);
                }
            }
        }

        // cross-lane max over the 16 j-columns, then store (lane c==p owns its rows' n1inv)
#pragma unroll
        for (int m = 1; m <= 8; m <<= 1)
#pragma unroll
            for (int pq = 0; pq < 2; pq++)
#pragma unroll
                for (int it = 0; it < 2; it++)
#pragma unroll
                    for (int r = 0; r < 4; r++)
                        rmax[pq][it][r] = fmaxf(rmax[pq][it][r], __shfl_xor(rmax[pq][it][r], m));

#pragma unroll
        for (int pq = 0; pq < 2; pq++) {
            const int p = p0 + pq;
            if (c == p) {
#pragma unroll
                for (int it = 0; it < 2; it++)
#pragma unroll
                    for (int r = 0; r < 4; r++) {
                        int i = i0 + ws * 32 + it * 16 + quad * 4 + r;   // always < 200
                        part[((size_t)jblk * BBATCH + b) * (LL * PP) + (size_t)i * PP + p] =
                            rmax[pq][it][r] * n1inv_reg[it][r];
                    }
            }
        }
    }
}

// ---------------- reduce: out = max over the two j-windows ------------------------------
__global__ __launch_bounds__(256) void reduce_kernel(const float* __restrict__ part,
                                                     float* __restrict__ out) {
    int tid = blockIdx.x * 256 + threadIdx.x;
    if (tid >= BBATCH * LL * PP) return;
    out[tid] = fmaxf(part[tid], part[(size_t)BBATCH * LL * PP + tid]);
}

extern "C" void kernel_launch(void* const* d_in, const int* in_sizes, int n_in,
                              void* d_out, int out_size, void* d_ws, size_t ws_size,
                              hipStream_t stream) {
    const float* sent1  = (const float*)d_in[0];   // (64,200,300) f32
    const float* sent2  = (const float*)d_in[1];   // (64,200,300) f32
    const float* kernel = (const float*)d_in[2];   // (16,300)     f32
    float* out = (float*)d_out;                    // (64,200,16)  f32

    char* ws = (char*)d_ws;
    _Float16* h1   = (_Float16*)ws;  ws += (size_t)BBATCH * LL * KG * 2;   // 8.19 MB
    _Float16* h2   = (_Float16*)ws;  ws += (size_t)BBATCH * LL * KG * 2;   // 8.19 MB
    _Float16* ksqt = (_Float16*)ws;  ws += 640 * 8 * 2;                    // 10 KB
    float*    part = (float*)ws;     // 2*64*200*16 f32 = 1.64 MB  (total ~18 MB)

    prep_kernel<<<2048, 256, 0, stream>>>(sent1, sent2, kernel, h1, h2, ksqt);

    const int lds_bytes = (128 * PS + 112 * PS + 112 * PP) * 2;   // 161,024 B
    hipFuncSetAttribute((const void*)maxsim_kernel,
                        hipFuncAttributeMaxDynamicSharedMemorySize, lds_bytes);
    maxsim_kernel<<<dim3(256, 1, 1), 512, lds_bytes, stream>>>(h1, h2, ksqt, part);

    int nout = BBATCH * LL * PP;
    reduce_kernel<<<(nout + 255) / 256, 256, 0, stream>>>(part, out);
}